// Round 20
// baseline (132.244 us; speedup 1.0000x reference)
//
#include <hip/hip_runtime.h>
#include <math.h>

#define BB 512
#define DD 512
#define KK 93431
#define KPAD 93440

#define S_SCALEf 64.0f
#define COS_Mf   0.87758256189037276f   /* cos(0.5) */
#define SIN_Mf   0.47942553860420301f   /* sin(0.5) */
#define THRESHf (-0.87758256189037276f) /* cos(pi-0.5) */
#define MMf      0.23971276930210151f   /* sin(pi-0.5)*0.5 */
#define EPSf     0.1f
#define MFIXf    65.0f

#define KSCALE 64.0f     /* kernel pre-scale before fp8 quantization */
#define XSCALE 16.0f     /* xn pre-scale before fp8 quantization */
#define INV_KX (1.0f / (KSCALE * XSCALE))

typedef float f32x4 __attribute__((ext_vector_type(4)));
typedef long  l64x2 __attribute__((ext_vector_type(2)));

__device__ __forceinline__ unsigned pack4_fp8(float a, float b, float c, float d) {
    unsigned v = 0;
    v = __builtin_amdgcn_cvt_pk_fp8_f32(a, b, v, false);  // bytes 0-1
    v = __builtin_amdgcn_cvt_pk_fp8_f32(c, d, v, true);   // bytes 2-3
    return v;
}

__device__ __forceinline__ void gload16(const void* g, void* l) {
    __builtin_amdgcn_global_load_lds(
        (const __attribute__((address_space(1))) unsigned int*)g,
        (__attribute__((address_space(3))) unsigned int*)l, 16, 0, 0);
}

// ---- kernel 1: row-normalize x -> xn (f32) + xnf8f (fp8 x16, MFMA-FRAGMENT order) ----
// chunk index ci = ((row>>4)*8 + kt64)*64 + (row&15) + (kq<<4); 16B chunk holds
// elements kt64*64 + kq*8..+7 (low 8B) and kt64*64 + (kq+4)*8..+7 (high 8B).
__global__ void rownorm_k(const float* __restrict__ x, float* __restrict__ xn,
                          unsigned char* __restrict__ xnf8f) {
    int b = blockIdx.x;
    int t = threadIdx.x; // 256
    float v0 = x[b * DD + t];
    float v1 = x[b * DD + t + 256];
    float ss = v0 * v0 + v1 * v1;
    for (int off = 32; off; off >>= 1) ss += __shfl_down(ss, off);
    __shared__ float wred[4];
    __shared__ float s_inv;
    __shared__ float rbF[512];
    if ((t & 63) == 0) wred[t >> 6] = ss;
    __syncthreads();
    if (t == 0) s_inv = rsqrtf(wred[0] + wred[1] + wred[2] + wred[3]);
    __syncthreads();
    float inv = s_inv;
    float a0 = v0 * inv, a1 = v1 * inv;
    xn[b * DD + t]       = a0;
    xn[b * DD + t + 256] = a1;
    rbF[t]       = a0;
    rbF[t + 256] = a1;
    __syncthreads();
    if (t < 32) {
        int kt64 = t >> 2, kq = t & 3;
        const int lo = kt64 * 64 + kq * 8;
        const int hi = kt64 * 64 + (kq + 4) * 8;
        unsigned w0 = pack4_fp8(XSCALE * rbF[lo + 0], XSCALE * rbF[lo + 1],
                                XSCALE * rbF[lo + 2], XSCALE * rbF[lo + 3]);
        unsigned w1 = pack4_fp8(XSCALE * rbF[lo + 4], XSCALE * rbF[lo + 5],
                                XSCALE * rbF[lo + 6], XSCALE * rbF[lo + 7]);
        unsigned w2 = pack4_fp8(XSCALE * rbF[hi + 0], XSCALE * rbF[hi + 1],
                                XSCALE * rbF[hi + 2], XSCALE * rbF[hi + 3]);
        unsigned w3 = pack4_fp8(XSCALE * rbF[hi + 4], XSCALE * rbF[hi + 5],
                                XSCALE * rbF[hi + 6], XSCALE * rbF[hi + 7]);
        uint4 o = {w0, w1, w2, w3};
        size_t ci = ((size_t)(b >> 4) * 8 + kt64) * 64 + (b & 15) + (kq << 4);
        *reinterpret_cast<uint4*>(&xnf8f[ci * 16]) = o;
    }
}

// ---- kernel 2: transpose kernel -> fp8 (x64, chunk-interleaved), column sumsq ----
__global__ __launch_bounds__(256) void tcvt_k(const float* __restrict__ ker,
                                              unsigned char* __restrict__ kerf8,
                                              float* __restrict__ ssq) {
    __shared__ float tile[64][65];
    __shared__ float sp[256];
    int t = threadIdx.x;
    int c0 = blockIdx.x * 64;           // 1460 blocks cover KPAD
    int lc = t & 63;
    int dq = t >> 6;
    int gc = c0 + lc;
    bool valid = gc < KK;
    float ss = 0.f;

    for (int kt = 0; kt < 8; ++kt) {
        const int d0 = kt * 64;
        __syncthreads();
#pragma unroll
        for (int i = 0; i < 16; ++i) {
            int d = dq + i * 4;
            float v = valid ? ker[(size_t)(d0 + d) * KK + gc] : 0.f;
            tile[d][lc] = v;
            ss = fmaf(v, v, ss);
        }
        __syncthreads();
#pragma unroll
        for (int j = 0; j < 2; ++j) {
            int l = t + 256 * j;        // 0..511
            int c = l >> 3;             // col 0..63
            int ch = l & 7;             // chunk (d = d0 + ch*8 .. +7)
            float v[8];
#pragma unroll
            for (int e = 0; e < 8; ++e) v[e] = KSCALE * tile[ch * 8 + e][c];
            unsigned w0 = pack4_fp8(v[0], v[1], v[2], v[3]);
            unsigned w1 = pack4_fp8(v[4], v[5], v[6], v[7]);
            uint2 o = {w0, w1};
            int off = (ch < 4) ? ch * 16 : (ch - 4) * 16 + 8;
            *reinterpret_cast<uint2*>(&kerf8[(size_t)(c0 + c) * DD + kt * 64 + off]) = o;
        }
    }
    sp[t] = ss;
    __syncthreads();
    if (t < 64) ssq[c0 + t] = sp[t] + sp[t + 64] + sp[t + 128] + sp[t + 192];
}

// ---------------- kernel 3: target logits (label columns, fp32 — exact) ----------------
__global__ void target_k(const float* __restrict__ xn, const float* __restrict__ ker,
                         const float* __restrict__ ssq, const int* __restrict__ label,
                         float* __restrict__ tl) {
    int b = blockIdx.x;
    int lane = threadIdx.x; // 64
    int col = label[b];
    float acc = 0.f;
#pragma unroll
    for (int d = lane; d < DD; d += 64)
        acc = fmaf(xn[b * DD + d], ker[(size_t)d * KK + col], acc);
    for (int off = 32; off; off >>= 1) acc += __shfl_down(acc, off);
    if (lane == 0) {
        float c = acc * rsqrtf(ssq[col]);
        c = fminf(1.f, fmaxf(-1.f, c));
        tl[b] = c;
    }
}

// ---- kernel 4: scalars + ssq pad fix + accumulator zero ----
__global__ void scalar_k(const float* __restrict__ tl, const float* __restrict__ t_in,
                         float* __restrict__ ctm, float* __restrict__ ftl,
                         float* __restrict__ tnew, float* __restrict__ ssq,
                         float* __restrict__ gse, float* __restrict__ gsl) {
    int t = threadIdx.x; // 512
    float v = tl[t];
    __shared__ float red[8];
    __shared__ float s_tn;
    float s = v;
    for (int off = 32; off; off >>= 1) s += __shfl_down(s, off);
    if ((t & 63) == 0) red[t >> 6] = s;
    __syncthreads();
    if (t == 0) {
        float tot = 0.f;
        for (int i = 0; i < 8; ++i) tot += red[i];
        s_tn = (tot / 512.0f) * 0.01f + 0.99f * t_in[0];
        tnew[0] = s_tn;
    }
    __syncthreads();
    float st = sqrtf(fmaxf(0.f, 1.f - v * v));
    float cm = v * COS_Mf - st * SIN_Mf;
    ctm[t] = cm;
    ftl[t] = (v > THRESHf) ? cm : (v - MMf);
    gse[t] = 0.f;
    gsl[t] = 0.f;
    if (t < KPAD - KK) ssq[KK + t] = 1.f;   // pad cols: kerf8 rows are 0 -> logit 0
}

// ---- kernel 5: A-in-registers fp8 GEMM, 32-col panels, 4 blocks/CU.
//      1024 blocks: row-group g (128 rows, 8 waves x 16 rows, a2 = 32 VGPR/lane)
//      x stream s (panels s, s+256, ...).  B panel = 32 cols x 512 k fp8 = 16 KB,
//      double-buffered (32 KB LDS + 2KB aux -> 4 blocks/CU, 16 waves/CU).
//      Counted vmcnt(2): next panel's 2 loads stay in flight across compute.
#define NPAN 2920            /* KPAD / 32 */
#define NSTR 256

__global__ __launch_bounds__(512, 4) void gemm_k(
    const unsigned char* __restrict__ xnf8f,   // [512 rows] fp8 fragment-order
    const unsigned char* __restrict__ kerf8,   // [KPAD][512] fp8 (x64), interleaved
    const float* __restrict__ ssq,
    const int* __restrict__ label,
    const float* __restrict__ ctm, const float* __restrict__ ftl,
    const float* __restrict__ tnew,
    float* __restrict__ gse, float* __restrict__ gsl)
{
    __shared__ __align__(16) unsigned char Bs[2][32 * 512];  // 2 x 16 KB
    __shared__ float ctm_s[128], ftl_s[128];
    __shared__ int   lbl_s[128];

    // bijective XCD swizzle (1024 % 8 == 0); row-group inner (B-panel L2 share)
    int wg = blockIdx.x;
    int id = (wg & 7) * 128 + (wg >> 3);
    const int g = id & 3;              // row group: rows g*128 .. +127
    const int s = id >> 2;             // panel stream 0..255
    const int row0 = g * 128;

    const int t = threadIdx.x;         // 512
    const int lane = t & 63;
    const int w = t >> 6;              // wave owns rows row0 + w*16 .. +15
    const int cp0 = lane & 15;
    const int kq = lane >> 4;          // 0..3

    if (t < 128) {
        int r = row0 + t;
        ctm_s[t] = ctm[r]; ftl_s[t] = ftl[r]; lbl_s[t] = label[r];
    }
    const float tn = tnew[0];

    // ---- A fragments: 16 rows x 512 k per wave = 32 VGPRs/lane, loaded once ----
    l64x2 a2[8];
    {
        const unsigned char* base =
            xnf8f + (size_t)((g * 8 + w) * 8) * 64 * 16;
#pragma unroll
        for (int kt = 0; kt < 8; ++kt)
            a2[kt] = *reinterpret_cast<const l64x2*>(
                base + ((size_t)kt * 64 + lane) * 16);
    }
#pragma unroll
    for (int kt = 0; kt < 8; ++kt)
        asm volatile("" :: "v"(__builtin_bit_cast(f32x4, a2[kt])));
    __builtin_amdgcn_sched_barrier(0);

    const int np = (s < NPAN - 11 * NSTR) ? 12 : 11;   // 104 streams get 12 panels

    // stage panel pv (col block pv*32) into buffer q: 1024 16B-chunks, 2/thread.
    // chunk l: col c = l>>5, slot sl = l&31; source slot = sl ^ (c&31) (both-sides XOR).
#define STAGEB(pv, q)                                                          \
    {                                                                          \
        const size_t pb = (size_t)(pv) * 32 * 512;                             \
        _Pragma("unroll")                                                      \
        for (int j = 0; j < 2; ++j) {                                          \
            const int l = t + 512 * j;                                         \
            const int c = l >> 5, sl = l & 31;                                 \
            const int ps = sl ^ (c & 31);                                      \
            gload16(&kerf8[pb + (size_t)c * 512 + ps * 16],                    \
                    (void*)&Bs[q][l * 16]);                                    \
        }                                                                      \
    }

    // ---- prologue: stage panel s -> buf 0; drain everything; barrier ----
    STAGEB(s, 0);
    __builtin_amdgcn_sched_barrier(0);
    asm volatile("s_waitcnt vmcnt(0) lgkmcnt(0)" ::: "memory");
    __builtin_amdgcn_s_barrier();

    float regse[4] = {0.f, 0.f, 0.f, 0.f};
    float regsl[4] = {0.f, 0.f, 0.f, 0.f};

    int buf = 0;
    for (int pi = 0; pi < np; ++pi) {
        const int p = s + pi * NSTR;
        // 1. ssq for this panel (2 loads; oldest -> drained by counted wait)
        float sq2[2];
#pragma unroll
        for (int fc = 0; fc < 2; ++fc)
            sq2[fc] = ssq[p * 32 + fc * 16 + cp0];
        // 2. stage next panel into the other buffer; counted wait
        if (pi + 1 < np) {
            STAGEB(p + NSTR, buf ^ 1);
            __builtin_amdgcn_sched_barrier(0);
            asm volatile("s_waitcnt vmcnt(2)" ::: "memory");  // panel p + sq2 landed
        } else {
            __builtin_amdgcn_sched_barrier(0);
            asm volatile("s_waitcnt vmcnt(0)" ::: "memory");
        }
        __builtin_amdgcn_s_barrier();

        // 3. compute panel p: 32 MFMA + 16 ds-reads per wave
        f32x4 acc[2];
        acc[0] = (f32x4)0.f; acc[1] = (f32x4)0.f;
        const char* Bp = (const char*)&Bs[buf][0];
        __builtin_amdgcn_s_setprio(1);
#pragma unroll
        for (int kt = 0; kt < 8; ++kt) {
            l64x2 bv[2];
#pragma unroll
            for (int fc = 0; fc < 2; ++fc) {
                const int ct = fc * 16 + cp0;
                const int slot = (kt * 4 + kq) ^ (ct & 31);
                bv[fc] = *reinterpret_cast<const l64x2*>(Bp + ct * 512 + slot * 16);
            }
#pragma unroll
            for (int fc = 0; fc < 2; ++fc) {
                acc[fc] = __builtin_amdgcn_mfma_f32_16x16x32_fp8_fp8(
                    a2[kt][0], bv[fc][0], acc[fc], 0, 0, 0);
                acc[fc] = __builtin_amdgcn_mfma_f32_16x16x32_fp8_fp8(
                    a2[kt][1], bv[fc][1], acc[fc], 0, 0, 0);
            }
        }
        __builtin_amdgcn_s_setprio(0);

        // 4. fused CurricularFace transform; per-lane partials stay in registers
        float inv2[2] = { rsqrtf(sq2[0]) * INV_KX, rsqrtf(sq2[1]) * INV_KX };
#pragma unroll
        for (int reg = 0; reg < 4; ++reg) {
            const int rt = w * 16 + (kq << 2) + reg;     // block-local row
            float cm = ctm_s[rt], ft = ftl_s[rt];
            const int rel = lbl_s[rt] - (p * 32 + cp0);
            float se = 0.f, sl = 0.f;
#pragma unroll
            for (int fc = 0; fc < 2; ++fc) {
                float c = acc[fc][reg] * inv2[fc];
                c = fminf(1.f, fmaxf(-1.f, c));
                float v = (c > cm) ? c * (tn + c) : c;
                if (rel == fc * 16) v = ft;
                float lg = S_SCALEf * v;
                se += __expf(lg - MFIXf);    // pad cols: cos=0 -> exp(-65)~0, lg=0
                sl += lg;
            }
            regse[reg] += se;
            regsl[reg] += sl;
        }
        // 5. all waves done reading buf -> overwrite-safe next iteration
        __builtin_amdgcn_s_barrier();
        buf ^= 1;
    }
#undef STAGEB

    // ---- block-end reduction: 16 lanes -> row, one global atomic per row ----
#pragma unroll
    for (int reg = 0; reg < 4; ++reg) {
        float se = regse[reg], sl = regsl[reg];
#pragma unroll
        for (int off = 8; off; off >>= 1) {
            se += __shfl_down(se, off, 16);
            sl += __shfl_down(sl, off, 16);
        }
        if (cp0 == 0) {
            const int row = row0 + w * 16 + (kq << 2) + reg;
            atomicAdd(&gse[row], se);
            atomicAdd(&gsl[row], sl);
        }
    }
}

// ---------------- kernel 6: final loss ----------------
__global__ void loss_k(const float* __restrict__ gse, const float* __restrict__ gsl,
                       const float* __restrict__ ftl, float* __restrict__ out) {
    int t = threadIdx.x; // 512
    float lse = MFIXf + logf(gse[t]);
    float lbl_logit = S_SCALEf * ftl[t];
    float nll = (1.f - EPSf) * (lbl_logit - lse)
              + (EPSf / (float)KK) * (gsl[t] - (float)KK * lse);
    __shared__ float red[8];
    float s = nll;
    for (int off = 32; off; off >>= 1) s += __shfl_down(s, off);
    if ((t & 63) == 0) red[t >> 6] = s;
    __syncthreads();
    if (t == 0) {
        float tot = 0.f;
        for (int i = 0; i < 8; ++i) tot += red[i];
        out[0] = -(tot / 512.0f);
    }
}

extern "C" void kernel_launch(void* const* d_in, const int* in_sizes, int n_in,
                              void* d_out, int out_size, void* d_ws, size_t ws_size,
                              hipStream_t stream) {
    const float* x     = (const float*)d_in[0];
    const int*   label = (const int*)d_in[1];
    const float* ker   = (const float*)d_in[2];
    const float* t_in  = (const float*)d_in[3];
    float* out = (float*)d_out;

    float* ws   = (float*)d_ws;
    float* xn   = ws;                 // 262144 f32
    float* ssq  = xn + 262144;        // KPAD
    float* gse  = ssq + KPAD;         // 512
    float* gsl  = gse + 512;          // 512
    float* tl   = gsl + 512;          // 512
    float* ctm  = tl + 512;           // 512
    float* ftl  = ctm + 512;          // 512
    float* tnew = ftl + 512;          // 64
    unsigned char* xnf8f = (unsigned char*)(tnew + 64);      // 512*512 fp8 (frag order)
    unsigned char* kerf8 = xnf8f + (size_t)512 * 512;        // KPAD*512 fp8

    rownorm_k<<<BB, 256, 0, stream>>>(x, xn, xnf8f);
    tcvt_k<<<KPAD / 64, 256, 0, stream>>>(ker, kerf8, ssq);
    target_k<<<BB, 64, 0, stream>>>(xn, ker, ssq, label, tl);
    scalar_k<<<1, 512, 0, stream>>>(tl, t_in, ctm, ftl, tnew, ssq, gse, gsl);
    gemm_k<<<1024, 512, 0, stream>>>(xnf8f, kerf8, ssq, label, ctm, ftl, tnew, gse, gsl);
    loss_k<<<1, 512, 0, stream>>>(gse, gsl, ftl, out);
}

// Round 21
// 121.578 us; speedup vs baseline: 1.0877x; 1.0877x over previous
//
#include <hip/hip_runtime.h>
#include <math.h>

#define BB 512
#define DD 512
#define KK 93431
#define KPAD 93440

#define S_SCALEf 64.0f
#define COS_Mf   0.87758256189037276f   /* cos(0.5) */
#define SIN_Mf   0.47942553860420301f   /* sin(0.5) */
#define THRESHf (-0.87758256189037276f) /* cos(pi-0.5) */
#define MMf      0.23971276930210151f   /* sin(pi-0.5)*0.5 */
#define EPSf     0.1f
#define MFIXf    65.0f

#define KSCALE 64.0f     /* kernel pre-scale before fp8 quantization */
#define XSCALE 16.0f     /* xn pre-scale before fp8 quantization */
#define INV_KX (1.0f / (KSCALE * XSCALE))

typedef float f32x4 __attribute__((ext_vector_type(4)));
typedef long  l64x2 __attribute__((ext_vector_type(2)));

__device__ __forceinline__ unsigned pack4_fp8(float a, float b, float c, float d) {
    unsigned v = 0;
    v = __builtin_amdgcn_cvt_pk_fp8_f32(a, b, v, false);  // bytes 0-1
    v = __builtin_amdgcn_cvt_pk_fp8_f32(c, d, v, true);   // bytes 2-3
    return v;
}

__device__ __forceinline__ void gload16(const void* g, void* l) {
    __builtin_amdgcn_global_load_lds(
        (const __attribute__((address_space(1))) unsigned int*)g,
        (__attribute__((address_space(3))) unsigned int*)l, 16, 0, 0);
}

// ---- kernel 1: row-normalize x -> xn (f32) + xnf8f (fp8 x16, MFMA-FRAGMENT order) ----
// chunk index ci = ((row>>4)*8 + kt64)*64 + (row&15) + (kq<<4); 16B chunk holds
// elements kt64*64 + kq*8..+7 (low 8B) and kt64*64 + (kq+4)*8..+7 (high 8B).
__global__ void rownorm_k(const float* __restrict__ x, float* __restrict__ xn,
                          unsigned char* __restrict__ xnf8f) {
    int b = blockIdx.x;
    int t = threadIdx.x; // 256
    float v0 = x[b * DD + t];
    float v1 = x[b * DD + t + 256];
    float ss = v0 * v0 + v1 * v1;
    for (int off = 32; off; off >>= 1) ss += __shfl_down(ss, off);
    __shared__ float wred[4];
    __shared__ float s_inv;
    __shared__ float rbF[512];
    if ((t & 63) == 0) wred[t >> 6] = ss;
    __syncthreads();
    if (t == 0) s_inv = rsqrtf(wred[0] + wred[1] + wred[2] + wred[3]);
    __syncthreads();
    float inv = s_inv;
    float a0 = v0 * inv, a1 = v1 * inv;
    xn[b * DD + t]       = a0;
    xn[b * DD + t + 256] = a1;
    rbF[t]       = a0;
    rbF[t + 256] = a1;
    __syncthreads();
    if (t < 32) {
        int kt64 = t >> 2, kq = t & 3;
        const int lo = kt64 * 64 + kq * 8;
        const int hi = kt64 * 64 + (kq + 4) * 8;
        unsigned w0 = pack4_fp8(XSCALE * rbF[lo + 0], XSCALE * rbF[lo + 1],
                                XSCALE * rbF[lo + 2], XSCALE * rbF[lo + 3]);
        unsigned w1 = pack4_fp8(XSCALE * rbF[lo + 4], XSCALE * rbF[lo + 5],
                                XSCALE * rbF[lo + 6], XSCALE * rbF[lo + 7]);
        unsigned w2 = pack4_fp8(XSCALE * rbF[hi + 0], XSCALE * rbF[hi + 1],
                                XSCALE * rbF[hi + 2], XSCALE * rbF[hi + 3]);
        unsigned w3 = pack4_fp8(XSCALE * rbF[hi + 4], XSCALE * rbF[hi + 5],
                                XSCALE * rbF[hi + 6], XSCALE * rbF[hi + 7]);
        uint4 o = {w0, w1, w2, w3};
        size_t ci = ((size_t)(b >> 4) * 8 + kt64) * 64 + (b & 15) + (kq << 4);
        *reinterpret_cast<uint4*>(&xnf8f[ci * 16]) = o;
    }
}

// ---- kernel 2: transpose kernel -> fp8 (x64, chunk-interleaved), column sumsq ----
// One block per 64-col strip, all 8 k-tiles; ssq via plain store (r18-proven).
__global__ __launch_bounds__(256) void tcvt_k(const float* __restrict__ ker,
                                              unsigned char* __restrict__ kerf8,
                                              float* __restrict__ ssq) {
    __shared__ float tile[64][65];
    __shared__ float sp[256];
    int t = threadIdx.x;
    int c0 = blockIdx.x * 64;           // 1460 blocks cover KPAD
    int lc = t & 63;
    int dq = t >> 6;
    int gc = c0 + lc;
    bool valid = gc < KK;
    float ss = 0.f;

    for (int kt = 0; kt < 8; ++kt) {
        const int d0 = kt * 64;
        __syncthreads();
#pragma unroll
        for (int i = 0; i < 16; ++i) {
            int d = dq + i * 4;
            float v = valid ? ker[(size_t)(d0 + d) * KK + gc] : 0.f;
            tile[d][lc] = v;
            ss = fmaf(v, v, ss);
        }
        __syncthreads();
#pragma unroll
        for (int j = 0; j < 2; ++j) {
            int l = t + 256 * j;        // 0..511
            int c = l >> 3;             // col 0..63
            int ch = l & 7;             // chunk (d = d0 + ch*8 .. +7)
            float v[8];
#pragma unroll
            for (int e = 0; e < 8; ++e) v[e] = KSCALE * tile[ch * 8 + e][c];
            unsigned w0 = pack4_fp8(v[0], v[1], v[2], v[3]);
            unsigned w1 = pack4_fp8(v[4], v[5], v[6], v[7]);
            uint2 o = {w0, w1};
            int off = (ch < 4) ? ch * 16 : (ch - 4) * 16 + 8;
            *reinterpret_cast<uint2*>(&kerf8[(size_t)(c0 + c) * DD + kt * 64 + off]) = o;
        }
    }
    sp[t] = ss;
    __syncthreads();
    if (t < 64) ssq[c0 + t] = sp[t] + sp[t + 64] + sp[t + 128] + sp[t + 192];
}

// ---------------- kernel 3: target logits (label columns, fp32 — exact) ----------------
__global__ void target_k(const float* __restrict__ xn, const float* __restrict__ ker,
                         const float* __restrict__ ssq, const int* __restrict__ label,
                         float* __restrict__ tl) {
    int b = blockIdx.x;
    int lane = threadIdx.x; // 64
    int col = label[b];
    float acc = 0.f;
#pragma unroll
    for (int d = lane; d < DD; d += 64)
        acc = fmaf(xn[b * DD + d], ker[(size_t)d * KK + col], acc);
    for (int off = 32; off; off >>= 1) acc += __shfl_down(acc, off);
    if (lane == 0) {
        float c = acc * rsqrtf(ssq[col]);
        c = fminf(1.f, fmaxf(-1.f, c));
        tl[b] = c;
    }
}

// ---- kernel 4: scalars + ssq pad fix + accumulator zero ----
__global__ void scalar_k(const float* __restrict__ tl, const float* __restrict__ t_in,
                         float* __restrict__ ctm, float* __restrict__ ftl,
                         float* __restrict__ tnew, float* __restrict__ ssq,
                         float* __restrict__ gse, float* __restrict__ gsl) {
    int t = threadIdx.x; // 512
    float v = tl[t];
    __shared__ float red[8];
    __shared__ float s_tn;
    float s = v;
    for (int off = 32; off; off >>= 1) s += __shfl_down(s, off);
    if ((t & 63) == 0) red[t >> 6] = s;
    __syncthreads();
    if (t == 0) {
        float tot = 0.f;
        for (int i = 0; i < 8; ++i) tot += red[i];
        s_tn = (tot / 512.0f) * 0.01f + 0.99f * t_in[0];
        tnew[0] = s_tn;
    }
    __syncthreads();
    float st = sqrtf(fmaxf(0.f, 1.f - v * v));
    float cm = v * COS_Mf - st * SIN_Mf;
    ctm[t] = cm;
    ftl[t] = (v > THRESHf) ? cm : (v - MMf);
    gse[t] = 0.f;
    gsl[t] = 0.f;
    if (t < KPAD - KK) ssq[KK + t] = 1.f;   // pad cols: kerf8 rows are 0 -> logit 0
}

// ---- kernel 5: A-in-registers fp8 GEMM.  512 blocks (2/CU): row-group g (128 rows,
//      8 waves x 16 rows, a2 = 32 VGPR/lane) x stream s (panels s, s+128, ...).
//      B panel = 64 cols x 512 k fp8 = 32 KB, double-buffered (64 KB LDS); staged
//      ONCE per row-group device-wide (187 MB total).  Counted vmcnt(4): next
//      panel's 4 loads stay in flight across the compute.  (Round-19 optimum.)
#define NPAN 1460
#define NSTR 128

__global__ __launch_bounds__(512, 4) void gemm_k(
    const unsigned char* __restrict__ xnf8f,   // [512 rows] fp8 fragment-order
    const unsigned char* __restrict__ kerf8,   // [KPAD][512] fp8 (x64), interleaved
    const float* __restrict__ ssq,
    const int* __restrict__ label,
    const float* __restrict__ ctm, const float* __restrict__ ftl,
    const float* __restrict__ tnew,
    float* __restrict__ gse, float* __restrict__ gsl)
{
    __shared__ __align__(16) unsigned char Bs[2][64 * 512];  // 2 x 32 KB
    __shared__ float ctm_s[128], ftl_s[128];
    __shared__ int   lbl_s[128];

    // bijective XCD swizzle (512 % 8 == 0); row-group inner (B-panel L2 share)
    int wg = blockIdx.x;
    int id = (wg & 7) * 64 + (wg >> 3);
    const int g = id & 3;              // row group: rows g*128 .. +127
    const int s = id >> 2;             // panel stream 0..127
    const int row0 = g * 128;

    const int t = threadIdx.x;         // 512
    const int lane = t & 63;
    const int w = t >> 6;              // wave owns rows row0 + w*16 .. +15
    const int cp0 = lane & 15;
    const int kq = lane >> 4;          // 0..3

    if (t < 128) {
        int r = row0 + t;
        ctm_s[t] = ctm[r]; ftl_s[t] = ftl[r]; lbl_s[t] = label[r];
    }
    const float tn = tnew[0];

    // ---- A fragments: 16 rows x 512 k per wave = 32 VGPRs/lane, loaded once ----
    l64x2 a2[8];
    {
        const unsigned char* base =
            xnf8f + (size_t)((g * 8 + w) * 8) * 64 * 16;
#pragma unroll
        for (int kt = 0; kt < 8; ++kt)
            a2[kt] = *reinterpret_cast<const l64x2*>(
                base + ((size_t)kt * 64 + lane) * 16);
    }
#pragma unroll
    for (int kt = 0; kt < 8; ++kt)
        asm volatile("" :: "v"(__builtin_bit_cast(f32x4, a2[kt])));
    __builtin_amdgcn_sched_barrier(0);

    const int np = (s < NPAN - 11 * NSTR) ? 12 : 11;   // 52 streams get 12 panels

    // stage panel pv (col block pv*64) into buffer q: 2048 16B-chunks, 4/thread.
    // chunk l: col c = l>>5, slot sl = l&31; source slot = sl ^ (c&31) (both-sides XOR).
#define STAGEB(pv, q)                                                          \
    {                                                                          \
        const size_t pb = (size_t)(pv) * 64 * 512;                             \
        _Pragma("unroll")                                                      \
        for (int j = 0; j < 4; ++j) {                                          \
            const int l = t + 512 * j;                                         \
            const int c = l >> 5, sl = l & 31;                                 \
            const int ps = sl ^ (c & 31);                                      \
            gload16(&kerf8[pb + (size_t)c * 512 + ps * 16],                    \
                    (void*)&Bs[q][l * 16]);                                    \
        }                                                                      \
    }

    // ---- prologue: stage panel s -> buf 0; drain everything; barrier ----
    STAGEB(s, 0);
    __builtin_amdgcn_sched_barrier(0);
    asm volatile("s_waitcnt vmcnt(0) lgkmcnt(0)" ::: "memory");
    __builtin_amdgcn_s_barrier();

    float regse[4] = {0.f, 0.f, 0.f, 0.f};
    float regsl[4] = {0.f, 0.f, 0.f, 0.f};

    int buf = 0;
    for (int pi = 0; pi < np; ++pi) {
        const int p = s + pi * NSTR;
        // 1. ssq for this panel (oldest -> drained by this iter's counted wait)
        float sq4[4];
#pragma unroll
        for (int fc = 0; fc < 4; ++fc)
            sq4[fc] = ssq[p * 64 + fc * 16 + cp0];
        // 2. stage next panel into the other buffer; counted wait
        if (pi + 1 < np) {
            STAGEB(p + NSTR, buf ^ 1);
            __builtin_amdgcn_sched_barrier(0);
            asm volatile("s_waitcnt vmcnt(4)" ::: "memory");  // panel p + sq4 landed
        } else {
            __builtin_amdgcn_sched_barrier(0);
            asm volatile("s_waitcnt vmcnt(0)" ::: "memory");
        }
        __builtin_amdgcn_s_barrier();

        // 3. compute panel p: 64 MFMA + 32 ds-reads per wave
        f32x4 acc[4];
#pragma unroll
        for (int fc = 0; fc < 4; ++fc) acc[fc] = (f32x4)0.f;
        const char* Bp = (const char*)&Bs[buf][0];
        __builtin_amdgcn_s_setprio(1);
#pragma unroll
        for (int kt = 0; kt < 8; ++kt) {
            l64x2 bv[4];
#pragma unroll
            for (int fc = 0; fc < 4; ++fc) {
                const int ct = fc * 16 + cp0;
                const int slot = (kt * 4 + kq) ^ (ct & 31);
                bv[fc] = *reinterpret_cast<const l64x2*>(Bp + ct * 512 + slot * 16);
            }
#pragma unroll
            for (int fc = 0; fc < 4; ++fc) {
                acc[fc] = __builtin_amdgcn_mfma_f32_16x16x32_fp8_fp8(
                    a2[kt][0], bv[fc][0], acc[fc], 0, 0, 0);
                acc[fc] = __builtin_amdgcn_mfma_f32_16x16x32_fp8_fp8(
                    a2[kt][1], bv[fc][1], acc[fc], 0, 0, 0);
            }
        }
        __builtin_amdgcn_s_setprio(0);

        // 4. fused CurricularFace transform; per-lane partials stay in registers
        float inv4[4];
#pragma unroll
        for (int fc = 0; fc < 4; ++fc) inv4[fc] = rsqrtf(sq4[fc]) * INV_KX;
#pragma unroll
        for (int reg = 0; reg < 4; ++reg) {
            const int rt = w * 16 + (kq << 2) + reg;     // block-local row
            float cm = ctm_s[rt], ft = ftl_s[rt];
            const int rel = lbl_s[rt] - (p * 64 + cp0);
            float se = 0.f, sl = 0.f;
#pragma unroll
            for (int fc = 0; fc < 4; ++fc) {
                float c = acc[fc][reg] * inv4[fc];
                c = fminf(1.f, fmaxf(-1.f, c));
                float v = (c > cm) ? c * (tn + c) : c;
                if (rel == fc * 16) v = ft;
                float lg = S_SCALEf * v;
                se += __expf(lg - MFIXf);    // pad cols: cos=0 -> exp(-65)~0, lg=0
                sl += lg;
            }
            regse[reg] += se;
            regsl[reg] += sl;
        }
        // 5. all waves done reading buf -> overwrite-safe next iteration
        __builtin_amdgcn_s_barrier();
        buf ^= 1;
    }
#undef STAGEB

    // ---- block-end reduction: 16 lanes -> row, one global atomic per row ----
#pragma unroll
    for (int reg = 0; reg < 4; ++reg) {
        float se = regse[reg], sl = regsl[reg];
#pragma unroll
        for (int off = 8; off; off >>= 1) {
            se += __shfl_down(se, off, 16);
            sl += __shfl_down(sl, off, 16);
        }
        if (cp0 == 0) {
            const int row = row0 + w * 16 + (kq << 2) + reg;
            atomicAdd(&gse[row], se);
            atomicAdd(&gsl[row], sl);
        }
    }
}

// ---------------- kernel 6: final loss ----------------
__global__ void loss_k(const float* __restrict__ gse, const float* __restrict__ gsl,
                       const float* __restrict__ ftl, float* __restrict__ out) {
    int t = threadIdx.x; // 512
    float lse = MFIXf + logf(gse[t]);
    float lbl_logit = S_SCALEf * ftl[t];
    float nll = (1.f - EPSf) * (lbl_logit - lse)
              + (EPSf / (float)KK) * (gsl[t] - (float)KK * lse);
    __shared__ float red[8];
    float s = nll;
    for (int off = 32; off; off >>= 1) s += __shfl_down(s, off);
    if ((t & 63) == 0) red[t >> 6] = s;
    __syncthreads();
    if (t == 0) {
        float tot = 0.f;
        for (int i = 0; i < 8; ++i) tot += red[i];
        out[0] = -(tot / 512.0f);
    }
}

extern "C" void kernel_launch(void* const* d_in, const int* in_sizes, int n_in,
                              void* d_out, int out_size, void* d_ws, size_t ws_size,
                              hipStream_t stream) {
    const float* x     = (const float*)d_in[0];
    const int*   label = (const int*)d_in[1];
    const float* ker   = (const float*)d_in[2];
    const float* t_in  = (const float*)d_in[3];
    float* out = (float*)d_out;

    float* ws   = (float*)d_ws;
    float* xn   = ws;                 // 262144 f32
    float* ssq  = xn + 262144;        // KPAD
    float* gse  = ssq + KPAD;         // 512
    float* gsl  = gse + 512;          // 512
    float* tl   = gsl + 512;          // 512
    float* ctm  = tl + 512;           // 512
    float* ftl  = ctm + 512;          // 512
    float* tnew = ftl + 512;          // 64
    unsigned char* xnf8f = (unsigned char*)(tnew + 64);      // 512*512 fp8 (frag order)
    unsigned char* kerf8 = xnf8f + (size_t)512 * 512;        // KPAD*512 fp8

    rownorm_k<<<BB, 256, 0, stream>>>(x, xn, xnf8f);
    tcvt_k<<<KPAD / 64, 256, 0, stream>>>(ker, kerf8, ssq);
    target_k<<<BB, 64, 0, stream>>>(xn, ker, ssq, label, tl);
    scalar_k<<<1, 512, 0, stream>>>(tl, t_in, ctm, ftl, tnew, ssq, gse, gsl);
    gemm_k<<<512, 512, 0, stream>>>(xnf8f, kerf8, ssq, label, ctm, ftl, tnew, gse, gsl);
    loss_k<<<1, 512, 0, stream>>>(gse, gsl, ftl, out);
}